// Round 7
// baseline (925.768 us; speedup 1.0000x reference)
//
#include <hip/hip_runtime.h>
#include <math.h>

// Problem constants (fixed by reference)
#define DIMD 256
#define KCODES 4096
#define NROWS 65536
#define QN (NROWS * DIMD)   // 16777216 quantized elements

// ---------------- pass1 (bf16 MFMA prune) parameters ----------------
constexpr int P1_BM = 128;     // rows per block (8 waves, 2x2-per-halfgrid tiling)
constexpr int P1_BN = 128;     // codes per N-tile
constexpr int NT    = KCODES / P1_BN;   // 32 N-tiles
// Dot-scale margin: candidate iff dot > running_global_prefix_max - TAU2.
// Error stack (dot scale): bf16 operand rounding <=2.3e-4 (worst), np fp32
// quantization ~3e-5, dropped se <=0.8e-5  ->  TAU2 = 7.5e-4 is ~2.8x margin.
// Prefix max <= final max at every collection point -> superset of the
// final-max candidate set (E ~ 7/row). Stored word packs the MFMA dot
// (top-20 fp32 bits) + 12-bit code; pass2 recovers the FINAL max and
// re-filters to ~3.5/row before the exact re-rank. Key truncation < 2.5e-6
// covered by the +1e-5 pass2 margin.
constexpr float TAU2 = 7.5e-4f;
constexpr float TAU2B = TAU2 + 1e-5f;   // pass2 re-filter margin (key truncation)
constexpr int CAP   = 48;      // candidate slots per row (overflow -> exact fallback)
constexpr int NS    = 8;       // pass2 LDS staging slots (survivors E~3.5)

typedef __attribute__((ext_vector_type(8))) short bf16x8;
typedef __attribute__((ext_vector_type(4))) float f32x4;

#define VM4() asm volatile("s_waitcnt vmcnt(4)" ::: "memory")
#define VM2() asm volatile("s_waitcnt vmcnt(2)" ::: "memory")
#define VM0() asm volatile("s_waitcnt vmcnt(0)" ::: "memory")

// RNE float -> bf16 bits (inputs finite; no NaN handling needed)
__device__ __forceinline__ unsigned short f2bf(float f) {
    unsigned int u = __builtin_bit_cast(unsigned int, f);
    u += 0x7fffu + ((u >> 16) & 1u);
    return (unsigned short)(u >> 16);
}

// Opaque barrier: forces v to be a rounded fp32 value (blocks FMA contraction)
__device__ __forceinline__ float opaque(float v) {
    asm volatile("" : "+v"(v));
    return v;
}

// async global->LDS, 16 B per lane, dest = wave-uniform base + lane*16
__device__ __forceinline__ void gload_lds16(const void* g, void* l) {
    __builtin_amdgcn_global_load_lds(
        (const __attribute__((address_space(1))) unsigned int*)g,
        (__attribute__((address_space(3))) unsigned int*)l, 16, 0, 0);
}

// ---------------------------------------------------------------- kernel Sx
// 8 lanes per row; lane j owns np accumulator r[j]. Bit-exact replication of
// the validated serial np pairwise_sum: r[j] chains are identical FP op
// sequences; the combine tree ((r0+r1)+(r2+r3))+((r4+r5)+(r6+r7)) is done
// with shfl_xor 1/2/4 (IEEE add commutative -> bit-identical on every lane).
__global__ void sx_kernel(const float* __restrict__ x, float* __restrict__ sx) {
    const int j   = threadIdx.x & 7;
    const int row = blockIdx.x * 32 + (threadIdx.x >> 3);
    const float* p = x + (size_t)row * DIMD;
    float total = 0.0f;
    #pragma unroll
    for (int half = 0; half < 2; ++half) {
        const float* b = p + half * 128;
        const float v0 = b[j];
        float r = opaque(v0 * v0);
        #pragma unroll
        for (int i = 8; i < 128; i += 8) {
            const float v = b[i + j];
            r += opaque(v * v);
        }
        const float s1  = r  + __shfl_xor(r, 1, 64);
        const float s2  = s1 + __shfl_xor(s1, 2, 64);
        const float res = s2 + __shfl_xor(s2, 4, 64);
        total = (half == 0) ? res : (total + res);
    }
    if (j == 0) sx[row] = total;
}

// ---------------------------------------------------------------- kernel Se
__global__ void se_kernel(const float* __restrict__ emb, float* __restrict__ se) {
    const int j   = threadIdx.x & 7;
    const int row = blockIdx.x * 32 + (threadIdx.x >> 3);
    const float* p = emb + (size_t)row * DIMD;
    float total = 0.0f;
    #pragma unroll
    for (int half = 0; half < 2; ++half) {
        const float* b = p + half * 128;
        const float v0 = b[j];
        float r = opaque(v0 * v0);
        #pragma unroll
        for (int i = 8; i < 128; i += 8) {
            const float v = b[i + j];
            r += opaque(v * v);
        }
        const float s1  = r  + __shfl_xor(r, 1, 64);
        const float s2  = s1 + __shfl_xor(s1, 2, 64);
        const float res = s2 + __shfl_xor(s2, 4, 64);
        total = (half == 0) ? res : (total + res);
    }
    if (j == 0) se[row] = total;
}

// ---------------------------------------------------------------- conv emb->bf16
__global__ void conv_emb_kernel(const float* __restrict__ emb, unsigned short* __restrict__ embh) {
    const int i = blockIdx.x * blockDim.x + threadIdx.x;  // float4 index
    const float4 v = ((const float4*)emb)[i];
    ushort4 h;
    h.x = f2bf(v.x); h.y = f2bf(v.y); h.z = f2bf(v.z); h.w = f2bf(v.w);
    ((ushort4*)embh)[i] = h;
}

// ---------------------------------------------------------------- kernel P1
// Single-pass bf16 MFMA prune, v5 (8-wave block, LDS candidate buffer):
//  - 512 threads, BM=128 rows. Wave w = (wr=w>>1, wc=w&1): 32 rows x 64 cols,
//    afr[2][8] = 64 VGPRs (spill-free shape, validated R5/R6).
//  - B staged via global_load_lds (16B) into a TRIPLE buffer, prefetch depth
//    2, counted vmcnt(4) per chunk (2 loads/stage/wave, 2 stages in flight).
//    NO stores in the K-loop: candidates go to an LDS buffer and are flushed
//    once at the end (coalesced), so vmcnt counts stay exact -- no VM0 drain.
//  - XOR swizzle on pre-swizzled GLOBAL source + swizzled read (validated):
//    phys slot p of code row c holds logical slot p ^ (c&7);
//    reader uses (ks*4+quad) ^ (lm&7).
__global__ __launch_bounds__(512, 4)
void pass1_kernel(const float* __restrict__ x, const unsigned short* __restrict__ embh,
                  unsigned int* __restrict__ cand, int* __restrict__ cnt_out) {
    __shared__ unsigned short Bs[3][8192];        // 3 x 16 KB: 128 codes x 64 k, swizzled
    __shared__ unsigned int cand_lds[P1_BM * CAP];// 24.6 KB candidate buffer
    __shared__ float part[8][32];                 // per-wave per-row tile max
    __shared__ float tilemax[P1_BM];              // merged tile max
    __shared__ int   cnts[P1_BM];

    const int t    = threadIdx.x;
    const int w    = t >> 6;
    const int lane = t & 63;
    const int quad = lane >> 4;
    const int lm   = lane & 15;
    const int wr   = w >> 1;           // row group: rows wr*32 .. +31
    const int wc   = w & 1;            // col half: cols wc*64 .. +63
    const int row0 = blockIdx.x * P1_BM;

    if (t < P1_BM) cnts[t] = 0;

    // ---- A panel -> registers: afr[f][c] = bf16(x[row0+wr*32+f*16+lm][c*32+quad*8 ..+7])
    bf16x8 afr[2][8];
    #pragma unroll
    for (int f = 0; f < 2; ++f) {
        const float* xr = x + (size_t)(row0 + wr * 32 + f * 16 + lm) * DIMD + quad * 8;
        #pragma unroll
        for (int c = 0; c < 8; ++c) {
            const float4 v0 = *(const float4*)(xr + c * 32);
            const float4 v1 = *(const float4*)(xr + c * 32 + 4);
            bf16x8 h;
            h[0] = (short)f2bf(v0.x); h[1] = (short)f2bf(v0.y);
            h[2] = (short)f2bf(v0.z); h[3] = (short)f2bf(v0.w);
            h[4] = (short)f2bf(v1.x); h[5] = (short)f2bf(v1.y);
            h[6] = (short)f2bf(v1.z); h[7] = (short)f2bf(v1.w);
            afr[f][c] = h;
        }
    }

    // stage chunk m (c0=(m>>2)*128 codes, kcb=(m&3)*64 k) into Bs[buf]
    // 16 segs / 8 waves = 2 gload_lds16 per wave per stage
    auto stage = [&](int buf, int m) {
        const int c0  = (m >> 2) * P1_BN;
        const int kcb = (m & 3) * 64;
        #pragma unroll
        for (int i = 0; i < 2; ++i) {
            const int seg  = i * 8 + w;                        // 0..15, wave-uniform
            const int code = seg * 8 + (lane >> 3);            // 0..127
            const int kk   = ((lane & 7) ^ ((lane >> 3) & 7)) * 8;  // pre-swizzled src
            const unsigned short* src = embh + (size_t)(c0 + code) * DIMD + kcb + kk;
            gload_lds16(src, &Bs[buf][seg * 512]);             // dest linear, 1 KB/issue
        }
    };

    stage(0, 0);
    stage(1, 1);
    int bc = 0;    // buffer holding the chunk we compute next

    float rmg[2][4];
    #pragma unroll
    for (int f = 0; f < 2; ++f)
        #pragma unroll
        for (int reg = 0; reg < 4; ++reg) rmg[f][reg] = -INFINITY;

    for (int tile = 0; tile < NT; ++tile) {
        const int c0 = tile * P1_BN;
        f32x4 acc[2][4];
        #pragma unroll
        for (int f = 0; f < 2; ++f)
            #pragma unroll
            for (int g = 0; g < 4; ++g) acc[f][g] = (f32x4){0.f, 0.f, 0.f, 0.f};

        #pragma unroll
        for (int kb = 0; kb < 4; ++kb) {
            const int m = tile * 4 + kb;
            __syncthreads();               // all waves done reading buf (m+2)%3 at m-1
            int st = bc + 2; if (st >= 3) st -= 3;
            if (m + 2 < NT * 4) {
                stage(st, m + 2);
                VM4();                     // wait my chunk-m loads (m+1,m+2 in flight)
            } else if (m + 2 == NT * 4) {
                VM2();                     // tail: only m+1's 2 loads newer
            } else {
                VM0();                     // last chunk
            }
            __syncthreads();               // all waves' chunk-m data in LDS

            // compute chunk m from Bs[bc] (K=64 = 2 MFMA K-steps)
            #pragma unroll
            for (int ks = 0; ks < 2; ++ks) {
                bf16x8 b[4];
                #pragma unroll
                for (int g = 0; g < 4; ++g) {
                    const int j = wc * 64 + g * 16 + lm;     // j&7 == lm&7
                    b[g] = *(const bf16x8*)
                        &Bs[bc][j * 64 + ((((ks << 2) + quad) ^ (lm & 7)) << 3)];
                }
                #pragma unroll
                for (int f = 0; f < 2; ++f)
                    #pragma unroll
                    for (int g = 0; g < 4; ++g)
                        acc[f][g] = __builtin_amdgcn_mfma_f32_16x16x32_bf16(
                            afr[f][kb * 2 + ks], b[g], acc[f][g], 0, 0, 0);
            }

            if (kb == 3) {
                // epilogue A: per-wave per-row max over this tile's 64 cols
                #pragma unroll
                for (int f = 0; f < 2; ++f) {
                    f32x4 mm4;
                    #pragma unroll
                    for (int reg = 0; reg < 4; ++reg) {
                        float mm = fmaxf(fmaxf(acc[f][0][reg], acc[f][1][reg]),
                                         fmaxf(acc[f][2][reg], acc[f][3][reg]));
                        #pragma unroll
                        for (int off = 1; off < 16; off <<= 1)
                            mm = fmaxf(mm, __shfl_xor(mm, off, 64));  // within quad group
                        mm4[reg] = mm;
                    }
                    if (lm == 0)
                        *(f32x4*)&part[w][f * 16 + quad * 4] = mm4;
                }
            }
            bc = (bc == 2) ? 0 : bc + 1;
        }

        // merge 2 col-waves per row group -> tile max (128 rows), then prefix max
        __syncthreads();
        if (t < P1_BM) {
            const int trg = t >> 5, loc = t & 31;
            tilemax[t] = fmaxf(part[trg * 2][loc], part[trg * 2 + 1][loc]);
        }
        __syncthreads();

        // epilogue B: threshold vs global prefix max (tile-inclusive), collect to LDS
        #pragma unroll
        for (int f = 0; f < 2; ++f) {
            const f32x4 tm = *(const f32x4*)&tilemax[wr * 32 + f * 16 + quad * 4];
            #pragma unroll
            for (int reg = 0; reg < 4; ++reg) {
                rmg[f][reg] = fmaxf(rmg[f][reg], tm[reg]);
                const float thr = rmg[f][reg] - TAU2;
                const int r = wr * 32 + f * 16 + quad * 4 + reg;
                #pragma unroll
                for (int g = 0; g < 4; ++g) {
                    const float dv = acc[f][g][reg];
                    if (dv > thr) {
                        const int slot = atomicAdd(&cnts[r], 1);
                        if (slot < CAP) {
                            const unsigned int ub =
                                __builtin_bit_cast(unsigned int, fmaxf(dv, 0.0f));
                            cand_lds[r * CAP + slot] =
                                (ub & 0xFFFFF000u) |
                                (unsigned int)(c0 + wc * 64 + g * 16 + lm);
                        }
                    }
                }
            }
        }
    }
    __syncthreads();

    // flush: whole candidate buffer, coalesced (garbage beyond cnt never read)
    {
        const uint4* src = (const uint4*)cand_lds;
        uint4* dst = (uint4*)(cand + (size_t)row0 * CAP);
        #pragma unroll
        for (int i = 0; i < P1_BM * CAP / 4 / 512; ++i)
            dst[i * 512 + t] = src[i * 512 + t];
    }
    if (t < P1_BM) cnt_out[row0 + t] = (cnts[t] > CAP) ? -1 : cnts[t];
}

// ---------------------------------------------------------------- kernel P2 (fused)
// Re-filter stored candidates against the FINAL max dot (present among the
// stored keys), stage surviving emb rows into LDS via async global_load_lds
// (all issues back-to-back, ONE vmcnt(0) -- single latency round), then run
// the exact np-semantics re-rank from LDS: dist = fl(fl(sx-2*dot)+se),
// dot = sequential fp32 FMA chain (validated R5/R6). The winner's slot is
// carried through the argmin so the quantized row is read back from LDS
// (no second global gather). Writes quantized + idx + per-row loss partial.
// One wave per row.
__global__ __launch_bounds__(256, 4)
void pass2_kernel(const float* __restrict__ x, const float* __restrict__ emb,
                  const float* __restrict__ sx, const float* __restrict__ se,
                  const unsigned int* __restrict__ cand, const int* __restrict__ cnt,
                  float* __restrict__ out, float* __restrict__ partial) {
    __shared__ float4 xsh[4][64];
    __shared__ float4 esh[4][NS][64];     // staged survivor rows (1 KB each, linear)
    const int w = threadIdx.x >> 6, lane = threadIdx.x & 63;
    const int row = blockIdx.x * 4 + w;
    const int n = cnt[row];
    const float sxr = sx[row];
    const float4* emb4 = (const float4*)emb;

    const float4 myx = ((const float4*)(x + (size_t)row * DIMD))[lane];
    xsh[w][lane] = myx;
    const float4* xs4 = &xsh[w][0];

    float bestd = INFINITY;
    int   bestc = 0x7fffffff;
    int   wslot = 0x7fffffff;

    if (n >= 1 && n <= CAP) {
        float dtil = -INFINITY;
        int   code = 0;
        if (lane < n) {
            const unsigned int word = cand[(size_t)row * CAP + lane];
            dtil = __builtin_bit_cast(float, word & 0xFFFFF000u);
            code = (int)(word & 0xFFFu);
        }
        // wave max of stored (truncated) dots == final max - O(2.5e-6)
        float mx = dtil;
        #pragma unroll
        for (int off = 1; off < 64; off <<= 1)
            mx = fmaxf(mx, __shfl_xor(mx, off, 64));
        const bool active = (lane < n) && (dtil > mx - TAU2B);
        const unsigned long long mask = __ballot(active);
        const int nact = __popcll(mask);
        const int slot = __popcll(mask & ((1ull << lane) - 1ull));
        // async-stage up to NS surviving rows: issue all, wait once
        unsigned long long mm = mask;
        const int ns = nact < NS ? nact : NS;
        for (int i = 0; i < ns; ++i) {
            const int li = __ffsll(mm) - 1;
            mm &= mm - 1;
            const int bc = __shfl(code, li, 64);
            gload_lds16(emb4 + (size_t)bc * 64 + lane, &esh[w][i][0]);
        }
        VM0();
        if (active) {
            float a = 0.0f;
            if (slot < NS) {
                const float4* ep4 = &esh[w][slot][0];
                #pragma unroll
                for (int d4 = 0; d4 < DIMD / 4; ++d4) {
                    const float4 ev = ep4[d4];
                    const float4 xv = xs4[d4];
                    a = fmaf(xv.x, ev.x, a);
                    a = fmaf(xv.y, ev.y, a);
                    a = fmaf(xv.z, ev.z, a);
                    a = fmaf(xv.w, ev.w, a);
                }
            } else {  // rare: >NS survivors, read from global
                const float4* ep4 = emb4 + (size_t)code * 64;
                #pragma unroll
                for (int d4 = 0; d4 < DIMD / 4; ++d4) {
                    const float4 ev = ep4[d4];
                    const float4 xv = xs4[d4];
                    a = fmaf(xv.x, ev.x, a);
                    a = fmaf(xv.y, ev.y, a);
                    a = fmaf(xv.z, ev.z, a);
                    a = fmaf(xv.w, ev.w, a);
                }
            }
            const float t1 = sxr - 2.0f * a;   // fl(sx - 2*dot)
            bestd = t1 + se[code];             // fl(t1 + se)
            bestc = code;
            wslot = slot;
        }
    } else {
        // overflow / safety fallback: full exact scan (ascending per lane)
        for (int c = lane; c < KCODES; c += 64) {
            const float* ep = emb + (size_t)c * DIMD;
            float a = 0.0f;
            for (int d4 = 0; d4 < DIMD / 4; ++d4) {
                const float4 xv = xs4[d4];
                const float4 ev = ((const float4*)ep)[d4];
                a = fmaf(xv.x, ev.x, a);
                a = fmaf(xv.y, ev.y, a);
                a = fmaf(xv.z, ev.z, a);
                a = fmaf(xv.w, ev.w, a);
            }
            const float t1 = sxr - 2.0f * a;
            const float dd = t1 + se[c];
            if (dd < bestd || (dd == bestd && c < bestc)) { bestd = dd; bestc = c; }
        }
    }
    // wave argmin, lexicographic (value, code): np first-occurrence semantics
    #pragma unroll
    for (int off = 32; off > 0; off >>= 1) {
        const float od = __shfl_down(bestd, off, 64);
        const int   oc = __shfl_down(bestc, off, 64);
        const int   os = __shfl_down(wslot, off, 64);
        if (od < bestd || (od == bestd && oc < bestc)) {
            bestd = od; bestc = oc; wslot = os;
        }
    }
    bestc = __shfl(bestc, 0, 64);   // broadcast winner
    wslot = __shfl(wslot, 0, 64);

    // fused epilogue: quantized row (from LDS when staged), idx, loss partial
    const float4 e4 = (wslot < NS) ? esh[w][wslot][lane]
                                   : emb4[(size_t)bestc * 64 + lane];
    ((float4*)(out + (size_t)row * DIMD))[lane] = e4;
    const float dx = e4.x - myx.x, dy = e4.y - myx.y,
                dz = e4.z - myx.z, dw = e4.w - myx.w;
    float s = dx * dx + dy * dy + dz * dz + dw * dw;
    #pragma unroll
    for (int off = 32; off > 0; off >>= 1) s += __shfl_down(s, off, 64);
    if (lane == 0) {
        partial[row] = s;
        out[QN + 1 + row] = (float)bestc;
    }
}

// ---------------------------------------------------------------- kernel L
// reduce 65536 per-row fp32 partials -> loss (LDS tree, double accum)
__global__ void loss_reduce_kernel(const float* __restrict__ partial, float* __restrict__ out) {
    const int t = threadIdx.x;           // 256 threads, 1 block
    double s = 0.0;
    for (int i = t; i < NROWS; i += 256) s += (double)partial[i];
    __shared__ double tsum[256];
    tsum[t] = s;
    __syncthreads();
    #pragma unroll
    for (int off = 128; off > 0; off >>= 1) {
        if (t < off) tsum[t] += tsum[t + off];
        __syncthreads();
    }
    if (t == 0) out[QN] = (float)(tsum[0] * (1.25 / (double)QN));
}

// ---------------------------------------------------------------- launcher
extern "C" void kernel_launch(void* const* d_in, const int* in_sizes, int n_in,
                              void* d_out, int out_size, void* d_ws, size_t ws_size,
                              hipStream_t stream) {
    const float* x   = (const float*)d_in[0];   // [65536, 256]
    const float* emb = (const float*)d_in[1];   // [4096, 256]
    float* out = (float*)d_out;                 // q[16777216] | loss[1] | idx[65536]

    char* ws = (char*)d_ws;
    unsigned short* embh = (unsigned short*)ws;           ws += (size_t)KCODES * DIMD * 2; // 2 MB
    float* sx  = (float*)ws;                              ws += (size_t)NROWS * 4;         // 256 KB
    float* se  = (float*)ws;                              ws += (size_t)KCODES * 4;        // 16 KB
    unsigned int* cand = (unsigned int*)ws;               ws += (size_t)NROWS * CAP * 4;   // 12.6 MB
    int*   cnt  = (int*)ws;                               ws += (size_t)NROWS * 4;         // 256 KB
    float* partial = (float*)ws;                                                           // 256 KB

    conv_emb_kernel<<<KCODES * DIMD / 4 / 256, 256, 0, stream>>>(emb, embh);
    sx_kernel<<<NROWS / 32, 256, 0, stream>>>(x, sx);
    se_kernel<<<KCODES / 32, 256, 0, stream>>>(emb, se);
    pass1_kernel<<<NROWS / P1_BM, 512, 0, stream>>>(x, embh, cand, cnt);
    pass2_kernel<<<NROWS / 4, 256, 0, stream>>>(x, emb, sx, se, cand, cnt, out, partial);
    loss_reduce_kernel<<<1, 256, 0, stream>>>(partial, out);
}

// Round 8
// 743.989 us; speedup vs baseline: 1.2443x; 1.2443x over previous
//
#include <hip/hip_runtime.h>
#include <math.h>

// Problem constants (fixed by reference)
#define DIMD 256
#define KCODES 4096
#define NROWS 65536
#define QN (NROWS * DIMD)   // 16777216 quantized elements

// ---------------- pass1 (bf16 MFMA prune) parameters ----------------
constexpr int P1_BM = 64;      // rows per block (4 waves, 2x2 tiling)
constexpr int P1_BN = 128;     // codes per N-tile
constexpr int NT    = KCODES / P1_BN;   // 32 N-tiles
constexpr int NCHUNK = NT * 2;          // 64 chunks of 128 codes x 128 k
// Dot-scale margin: candidate iff dot > running_global_prefix_max - TAU2.
// Error stack (dot scale): bf16 operand rounding <=2.3e-4 (worst), np fp32
// quantization ~3e-5, dropped se <=0.8e-5  ->  TAU2 = 7.5e-4 is ~2.8x margin.
// Prefix max <= final max at every collection point -> superset of the
// final-max candidate set (E ~ 7/row). Stored word packs the MFMA dot
// (top-20 fp32 bits) + 12-bit code; pass2 recovers the FINAL max and
// re-filters to ~3.5/row before the exact re-rank. Key truncation < 2.5e-6
// covered by the +1e-5 pass2 margin.
constexpr float TAU2 = 7.5e-4f;
constexpr float TAU2B = TAU2 + 1e-5f;   // pass2 re-filter margin (key truncation)
constexpr int CAP   = 48;      // candidate slots per row (overflow -> exact fallback)
constexpr int NS    = 8;       // pass2 LDS staging slots (survivors E~3.5)

typedef __attribute__((ext_vector_type(8))) short bf16x8;
typedef __attribute__((ext_vector_type(4))) float f32x4;

#define VM8() asm volatile("s_waitcnt vmcnt(8)" ::: "memory")
#define VM0() asm volatile("s_waitcnt vmcnt(0)" ::: "memory")

// RNE float -> bf16 bits (inputs finite; no NaN handling needed)
__device__ __forceinline__ unsigned short f2bf(float f) {
    unsigned int u = __builtin_bit_cast(unsigned int, f);
    u += 0x7fffu + ((u >> 16) & 1u);
    return (unsigned short)(u >> 16);
}

// Opaque barrier: forces v to be a rounded fp32 value (blocks FMA contraction)
__device__ __forceinline__ float opaque(float v) {
    asm volatile("" : "+v"(v));
    return v;
}

// async global->LDS, 16 B per lane, dest = wave-uniform base + lane*16
__device__ __forceinline__ void gload_lds16(const void* g, void* l) {
    __builtin_amdgcn_global_load_lds(
        (const __attribute__((address_space(1))) unsigned int*)g,
        (__attribute__((address_space(3))) unsigned int*)l, 16, 0, 0);
}

// ---------------------------------------------------------------- kernel Sx
// 8 lanes per row; lane j owns np accumulator r[j]. Bit-exact replication of
// the validated serial np pairwise_sum (combine tree via shfl_xor 1/2/4;
// IEEE add commutative -> bit-identical).
__global__ void sx_kernel(const float* __restrict__ x, float* __restrict__ sx) {
    const int j   = threadIdx.x & 7;
    const int row = blockIdx.x * 32 + (threadIdx.x >> 3);
    const float* p = x + (size_t)row * DIMD;
    float total = 0.0f;
    #pragma unroll
    for (int half = 0; half < 2; ++half) {
        const float* b = p + half * 128;
        const float v0 = b[j];
        float r = opaque(v0 * v0);
        #pragma unroll
        for (int i = 8; i < 128; i += 8) {
            const float v = b[i + j];
            r += opaque(v * v);
        }
        const float s1  = r  + __shfl_xor(r, 1, 64);
        const float s2  = s1 + __shfl_xor(s1, 2, 64);
        const float res = s2 + __shfl_xor(s2, 4, 64);
        total = (half == 0) ? res : (total + res);
    }
    if (j == 0) sx[row] = total;
}

// ---------------------------------------------------------------- kernel Se
__global__ void se_kernel(const float* __restrict__ emb, float* __restrict__ se) {
    const int j   = threadIdx.x & 7;
    const int row = blockIdx.x * 32 + (threadIdx.x >> 3);
    const float* p = emb + (size_t)row * DIMD;
    float total = 0.0f;
    #pragma unroll
    for (int half = 0; half < 2; ++half) {
        const float* b = p + half * 128;
        const float v0 = b[j];
        float r = opaque(v0 * v0);
        #pragma unroll
        for (int i = 8; i < 128; i += 8) {
            const float v = b[i + j];
            r += opaque(v * v);
        }
        const float s1  = r  + __shfl_xor(r, 1, 64);
        const float s2  = s1 + __shfl_xor(s1, 2, 64);
        const float res = s2 + __shfl_xor(s2, 4, 64);
        total = (half == 0) ? res : (total + res);
    }
    if (j == 0) se[row] = total;
}

// ---------------------------------------------------------------- conv emb->bf16
__global__ void conv_emb_kernel(const float* __restrict__ emb, unsigned short* __restrict__ embh) {
    const int i = blockIdx.x * blockDim.x + threadIdx.x;  // float4 index
    const float4 v = ((const float4*)emb)[i];
    ushort4 h;
    h.x = f2bf(v.x); h.y = f2bf(v.y); h.z = f2bf(v.z); h.w = f2bf(v.w);
    ((ushort4*)embh)[i] = h;
}

// ---------------------------------------------------------------- kernel P1
// Single-pass bf16 MFMA prune, v6 (R6's spill-free shape + stall removal):
//  - 256 threads, launch_bounds(256,2): the validated ~104-VGPR no-spill
//    point. Wave (wr,wc) owns 32 rows x 64 cols; afr[2][8] = 64 VGPRs.
//  - Chunks of 128 codes x 128 k (32 KB), DOUBLE-buffered: half the
//    barriers of the 64k version, 32 MFMA per barrier, prefetch distance
//    = one full chunk (> HBM latency). Counted vmcnt(8) per chunk.
//  - NO stores in the K-loop: candidates collect into LDS, one coalesced
//    flush at the end -> vmcnt counts exact, zero VM0 drains.
//  - 16-slot XOR swizzle, both sides (validated scheme): phys slot p of
//    code c holds logical slot p ^ (c&15); reader uses (ks*4+quad) ^ lm.
__global__ __launch_bounds__(256, 2)
void pass1_kernel(const float* __restrict__ x, const unsigned short* __restrict__ embh,
                  unsigned int* __restrict__ cand, int* __restrict__ cnt_out) {
    __shared__ unsigned short Bs[2][16384];       // 2 x 32 KB: 128 codes x 128 k, swizzled
    __shared__ unsigned int cand_lds[P1_BM * CAP];// 12.3 KB candidate buffer
    __shared__ float part[4][32];                 // per-wave per-row tile max
    __shared__ float tilemax[P1_BM];              // merged tile max
    __shared__ int   cnts[P1_BM];

    const int t    = threadIdx.x;
    const int w    = t >> 6;
    const int lane = t & 63;
    const int quad = lane >> 4;
    const int lm   = lane & 15;
    const int wr   = w >> 1;           // row group: rows wr*32 .. +31
    const int wc   = w & 1;            // col half: cols wc*64 .. +63
    const int row0 = blockIdx.x * P1_BM;

    if (t < P1_BM) cnts[t] = 0;

    // ---- A panel -> registers: afr[f][c] = bf16(x[row0+wr*32+f*16+lm][c*32+quad*8 ..+7])
    bf16x8 afr[2][8];
    #pragma unroll
    for (int f = 0; f < 2; ++f) {
        const float* xr = x + (size_t)(row0 + wr * 32 + f * 16 + lm) * DIMD + quad * 8;
        #pragma unroll
        for (int c = 0; c < 8; ++c) {
            const float4 v0 = *(const float4*)(xr + c * 32);
            const float4 v1 = *(const float4*)(xr + c * 32 + 4);
            bf16x8 h;
            h[0] = (short)f2bf(v0.x); h[1] = (short)f2bf(v0.y);
            h[2] = (short)f2bf(v0.z); h[3] = (short)f2bf(v0.w);
            h[4] = (short)f2bf(v1.x); h[5] = (short)f2bf(v1.y);
            h[6] = (short)f2bf(v1.z); h[7] = (short)f2bf(v1.w);
            afr[f][c] = h;
        }
    }

    // stage chunk m (c0=(m>>1)*128 codes, kcb=(m&1)*128 k) into Bs[buf]:
    // 32 segs of 1 KB; seg holds 4 codes x 16 phys slots of 16 B.
    // thread (seg=i*4+w, lane): code c = seg*4 + (lane>>4), phys slot p = lane&15,
    // source k-slot = p ^ (c&15)  (pre-swizzled source, linear LDS dest).
    auto stage = [&](int buf, int m) {
        const int c0  = (m >> 1) * P1_BN;
        const int kcb = (m & 1) * 128;
        #pragma unroll
        for (int i = 0; i < 8; ++i) {
            const int seg = i * 4 + w;                         // 0..31, wave-uniform
            const int c   = seg * 4 + (lane >> 4);             // 0..127
            const int kk  = ((lane & 15) ^ (c & 15)) * 8;      // shorts
            const unsigned short* src = embh + (size_t)(c0 + c) * DIMD + kcb + kk;
            gload_lds16(src, &Bs[buf][seg * 512]);             // 1 KB per issue
        }
    };

    stage(0, 0);
    int buf = 0;

    float rmg[2][4];
    #pragma unroll
    for (int f = 0; f < 2; ++f)
        #pragma unroll
        for (int reg = 0; reg < 4; ++reg) rmg[f][reg] = -INFINITY;

    for (int tile = 0; tile < NT; ++tile) {
        const int c0 = tile * P1_BN;
        f32x4 acc[2][4];
        #pragma unroll
        for (int f = 0; f < 2; ++f)
            #pragma unroll
            for (int g = 0; g < 4; ++g) acc[f][g] = (f32x4){0.f, 0.f, 0.f, 0.f};

        #pragma unroll
        for (int kb = 0; kb < 2; ++kb) {
            const int m = tile * 2 + kb;
            __syncthreads();               // A: all waves done reading buf^1
            if (m + 1 < NCHUNK) {
                stage(buf ^ 1, m + 1);
                VM8();                     // wait chunk-m loads (8 newer in flight)
            } else {
                VM0();                     // last chunk
            }
            __syncthreads();               // B: chunk m fully in LDS

            // compute chunk m from Bs[buf]: K=128 = 4 MFMA K-steps
            #pragma unroll
            for (int ks = 0; ks < 4; ++ks) {
                bf16x8 b[4];
                #pragma unroll
                for (int g = 0; g < 4; ++g) {
                    const int c = wc * 64 + g * 16 + lm;     // c&15 == lm
                    b[g] = *(const bf16x8*)
                        &Bs[buf][c * 128 + ((((ks << 2) + quad) ^ lm) << 3)];
                }
                #pragma unroll
                for (int f = 0; f < 2; ++f)
                    #pragma unroll
                    for (int g = 0; g < 4; ++g)
                        acc[f][g] = __builtin_amdgcn_mfma_f32_16x16x32_bf16(
                            afr[f][kb * 4 + ks], b[g], acc[f][g], 0, 0, 0);
            }
            buf ^= 1;
        }

        // epilogue A: per-wave per-row max over this tile's 64 cols
        #pragma unroll
        for (int f = 0; f < 2; ++f) {
            f32x4 mm4;
            #pragma unroll
            for (int reg = 0; reg < 4; ++reg) {
                float mm = fmaxf(fmaxf(acc[f][0][reg], acc[f][1][reg]),
                                 fmaxf(acc[f][2][reg], acc[f][3][reg]));
                #pragma unroll
                for (int off = 1; off < 16; off <<= 1)
                    mm = fmaxf(mm, __shfl_xor(mm, off, 64));  // within quad group
                mm4[reg] = mm;
            }
            if (lm == 0)
                *(f32x4*)&part[w][f * 16 + quad * 4] = mm4;
        }

        // merge 2 col-waves per row group -> tile max, then prefix max
        __syncthreads();
        if (t < P1_BM) {
            const int trg = t >> 5, loc = t & 31;
            tilemax[t] = fmaxf(part[trg * 2][loc], part[trg * 2 + 1][loc]);
        }
        __syncthreads();

        // epilogue B: threshold vs global prefix max (tile-inclusive), collect to LDS
        #pragma unroll
        for (int f = 0; f < 2; ++f) {
            const f32x4 tm = *(const f32x4*)&tilemax[wr * 32 + f * 16 + quad * 4];
            #pragma unroll
            for (int reg = 0; reg < 4; ++reg) {
                rmg[f][reg] = fmaxf(rmg[f][reg], tm[reg]);
                const float thr = rmg[f][reg] - TAU2;
                const int r = wr * 32 + f * 16 + quad * 4 + reg;
                #pragma unroll
                for (int g = 0; g < 4; ++g) {
                    const float dv = acc[f][g][reg];
                    if (dv > thr) {
                        const int slot = atomicAdd(&cnts[r], 1);
                        if (slot < CAP) {
                            const unsigned int ub =
                                __builtin_bit_cast(unsigned int, fmaxf(dv, 0.0f));
                            cand_lds[r * CAP + slot] =
                                (ub & 0xFFFFF000u) |
                                (unsigned int)(c0 + wc * 64 + g * 16 + lm);
                        }
                    }
                }
            }
        }
    }
    __syncthreads();

    // flush: whole candidate buffer, coalesced (slots >= cnt are never read;
    // pass2 loads them unconditionally but masks by lane < cnt)
    {
        const uint4* src = (const uint4*)cand_lds;
        uint4* dst = (uint4*)(cand + (size_t)row0 * CAP);
        #pragma unroll
        for (int i = 0; i < P1_BM * CAP / 4 / 256; ++i)
            dst[i * 256 + t] = src[i * 256 + t];
    }
    if (t < P1_BM) cnt_out[row0 + t] = (cnts[t] > CAP) ? -1 : cnts[t];
}

// ---------------------------------------------------------------- kernel P2 (fused)
// Re-filter stored candidates against the FINAL max dot (present among the
// stored keys), stage surviving emb rows into LDS via async global_load_lds
// (all issues back-to-back, ONE vmcnt(0)), then the exact np-semantics
// re-rank from LDS: dist = fl(fl(sx-2*dot)+se), dot = sequential fp32 FMA
// chain (validated R5/R6). cnt and cand words load in PARALLEL (cand is
// always fully written; garbage masked by lane<n). Winner's slot carried
// through the argmin -> quantized row read back from LDS. Writes quantized
// + idx + per-row loss partial. One wave per row.
__global__ __launch_bounds__(256, 4)
void pass2_kernel(const float* __restrict__ x, const float* __restrict__ emb,
                  const float* __restrict__ sx, const float* __restrict__ se,
                  const unsigned int* __restrict__ cand, const int* __restrict__ cnt,
                  float* __restrict__ out, float* __restrict__ partial) {
    __shared__ float4 xsh[4][64];
    __shared__ float4 esh[4][NS][64];     // staged survivor rows (1 KB each, linear)
    const int w = threadIdx.x >> 6, lane = threadIdx.x & 63;
    const int row = blockIdx.x * 4 + w;
    const int n = cnt[row];                                          // load 1
    const unsigned int word = cand[(size_t)row * CAP + lane];        // load 2 (parallel)
    const float sxr = sx[row];                                       // load 3 (parallel)
    const float4 myx = ((const float4*)(x + (size_t)row * DIMD))[lane]; // load 4
    const float4* emb4 = (const float4*)emb;

    xsh[w][lane] = myx;
    const float4* xs4 = &xsh[w][0];

    float bestd = INFINITY;
    int   bestc = 0x7fffffff;
    int   wslot = 0x7fffffff;

    if (n >= 1 && n <= CAP) {
        const float dtil = (lane < n)
            ? __builtin_bit_cast(float, word & 0xFFFFF000u) : -INFINITY;
        const int code = (int)(word & 0xFFFu);   // garbage if lane>=n (masked)
        // wave max of stored (truncated) dots == final max - O(2.5e-6)
        float mx = dtil;
        #pragma unroll
        for (int off = 1; off < 64; off <<= 1)
            mx = fmaxf(mx, __shfl_xor(mx, off, 64));
        const bool active = (lane < n) && (dtil > mx - TAU2B);
        const unsigned long long mask = __ballot(active);
        const int nact = __popcll(mask);
        const int slot = __popcll(mask & ((1ull << lane) - 1ull));
        // async-stage up to NS surviving rows: issue all, wait once
        unsigned long long mm = mask;
        const int ns = nact < NS ? nact : NS;
        for (int i = 0; i < ns; ++i) {
            const int li = __ffsll(mm) - 1;
            mm &= mm - 1;
            const int bc = __shfl(code, li, 64);
            gload_lds16(emb4 + (size_t)bc * 64 + lane, &esh[w][i][0]);
        }
        VM0();
        if (active) {
            float a = 0.0f;
            if (slot < NS) {
                const float4* ep4 = &esh[w][slot][0];
                #pragma unroll
                for (int d4 = 0; d4 < DIMD / 4; ++d4) {
                    const float4 ev = ep4[d4];
                    const float4 xv = xs4[d4];
                    a = fmaf(xv.x, ev.x, a);
                    a = fmaf(xv.y, ev.y, a);
                    a = fmaf(xv.z, ev.z, a);
                    a = fmaf(xv.w, ev.w, a);
                }
            } else {  // rare: >NS survivors, read from global
                const float4* ep4 = emb4 + (size_t)code * 64;
                #pragma unroll
                for (int d4 = 0; d4 < DIMD / 4; ++d4) {
                    const float4 ev = ep4[d4];
                    const float4 xv = xs4[d4];
                    a = fmaf(xv.x, ev.x, a);
                    a = fmaf(xv.y, ev.y, a);
                    a = fmaf(xv.z, ev.z, a);
                    a = fmaf(xv.w, ev.w, a);
                }
            }
            const float t1 = sxr - 2.0f * a;   // fl(sx - 2*dot)
            bestd = t1 + se[code];             // fl(t1 + se)
            bestc = code;
            wslot = slot;
        }
    } else {
        // overflow / safety fallback: full exact scan (ascending per lane)
        for (int c = lane; c < KCODES; c += 64) {
            const float* ep = emb + (size_t)c * DIMD;
            float a = 0.0f;
            for (int d4 = 0; d4 < DIMD / 4; ++d4) {
                const float4 xv = xs4[d4];
                const float4 ev = ((const float4*)ep)[d4];
                a = fmaf(xv.x, ev.x, a);
                a = fmaf(xv.y, ev.y, a);
                a = fmaf(xv.z, ev.z, a);
                a = fmaf(xv.w, ev.w, a);
            }
            const float t1 = sxr - 2.0f * a;
            const float dd = t1 + se[c];
            if (dd < bestd || (dd == bestd && c < bestc)) { bestd = dd; bestc = c; }
        }
    }
    // wave argmin, lexicographic (value, code): np first-occurrence semantics
    #pragma unroll
    for (int off = 32; off > 0; off >>= 1) {
        const float od = __shfl_down(bestd, off, 64);
        const int   oc = __shfl_down(bestc, off, 64);
        const int   os = __shfl_down(wslot, off, 64);
        if (od < bestd || (od == bestd && oc < bestc)) {
            bestd = od; bestc = oc; wslot = os;
        }
    }
    bestc = __shfl(bestc, 0, 64);   // broadcast winner
    wslot = __shfl(wslot, 0, 64);

    // fused epilogue: quantized row (from LDS when staged), idx, loss partial
    const float4 e4 = (wslot < NS) ? esh[w][wslot][lane]
                                   : emb4[(size_t)bestc * 64 + lane];
    ((float4*)(out + (size_t)row * DIMD))[lane] = e4;
    const float dx = e4.x - myx.x, dy = e4.y - myx.y,
                dz = e4.z - myx.z, dw = e4.w - myx.w;
    float s = dx * dx + dy * dy + dz * dz + dw * dw;
    #pragma unroll
    for (int off = 32; off > 0; off >>= 1) s += __shfl_down(s, off, 64);
    if (lane == 0) {
        partial[row] = s;
        out[QN + 1 + row] = (float)bestc;
    }
}

// ---------------------------------------------------------------- kernel L
// reduce 65536 per-row fp32 partials -> loss (LDS tree, double accum)
__global__ void loss_reduce_kernel(const float* __restrict__ partial, float* __restrict__ out) {
    const int t = threadIdx.x;           // 256 threads, 1 block
    double s = 0.0;
    for (int i = t; i < NROWS; i += 256) s += (double)partial[i];
    __shared__ double tsum[256];
    tsum[t] = s;
    __syncthreads();
    #pragma unroll
    for (int off = 128; off > 0; off >>= 1) {
        if (t < off) tsum[t] += tsum[t + off];
        __syncthreads();
    }
    if (t == 0) out[QN] = (float)(tsum[0] * (1.25 / (double)QN));
}

// ---------------------------------------------------------------- launcher
extern "C" void kernel_launch(void* const* d_in, const int* in_sizes, int n_in,
                              void* d_out, int out_size, void* d_ws, size_t ws_size,
                              hipStream_t stream) {
    const float* x   = (const float*)d_in[0];   // [65536, 256]
    const float* emb = (const float*)d_in[1];   // [4096, 256]
    float* out = (float*)d_out;                 // q[16777216] | loss[1] | idx[65536]

    char* ws = (char*)d_ws;
    unsigned short* embh = (unsigned short*)ws;           ws += (size_t)KCODES * DIMD * 2; // 2 MB
    float* sx  = (float*)ws;                              ws += (size_t)NROWS * 4;         // 256 KB
    float* se  = (float*)ws;                              ws += (size_t)KCODES * 4;        // 16 KB
    unsigned int* cand = (unsigned int*)ws;               ws += (size_t)NROWS * CAP * 4;   // 12.6 MB
    int*   cnt  = (int*)ws;                               ws += (size_t)NROWS * 4;         // 256 KB
    float* partial = (float*)ws;                                                           // 256 KB

    conv_emb_kernel<<<KCODES * DIMD / 4 / 256, 256, 0, stream>>>(emb, embh);
    sx_kernel<<<NROWS / 32, 256, 0, stream>>>(x, sx);
    se_kernel<<<KCODES / 32, 256, 0, stream>>>(emb, se);
    pass1_kernel<<<NROWS / P1_BM, 256, 0, stream>>>(x, embh, cand, cnt);
    pass2_kernel<<<NROWS / 4, 256, 0, stream>>>(x, emb, sx, se, cand, cnt, out, partial);
    loss_reduce_kernel<<<1, 256, 0, stream>>>(partial, out);
}